// Round 4
// baseline (576.050 us; speedup 1.0000x reference)
//
#include <hip/hip_runtime.h>

static constexpr int   kBatch   = 2097152;
static constexpr float kActScale = 1.0f / 12.0f;
static constexpr float kAct2     = 1.0f / 6.0f;   // 2*ACT_SCALE

// Device-global table:
// [0,1024)    spA0   (softplus(raw_A_0), row-major [i][j])
// [1024,2048) spA1
// [2048,3072) spA0T  (transposed)
// [3072,4096) spA1T
// [4096,4128) spAout
// [4128]      cref   (dW/dI1 at z0 = 0)
__device__ float g_tab[4136];

__device__ __forceinline__ float rcp_f(float x) { return __fdividef(1.0f, x); }

__device__ __forceinline__ float sp_only(float x) {
    float e = __expf(-fabsf(x));
    return fmaxf(x, 0.0f) + __logf(1.0f + e);
}
__device__ __forceinline__ float sig_only(float x) {
    float e = __expf(-fabsf(x));
    float r = rcp_f(1.0f + e);
    return (x >= 0.0f) ? r : e * r;
}
__device__ __forceinline__ float sp_sig(float x, float& sig) {
    float e  = __expf(-fabsf(x));
    float oe = 1.0f + e;
    float r  = rcp_f(oe);
    sig = (x >= 0.0f) ? r : e * r;
    return fmaxf(x, 0.0f) + __logf(oe);
}

// ---------------- prep: softplus tables + reference-gradient constant --------
__global__ __launch_bounds__(256) void icnn_prep(
    const float* __restrict__ rawA0, const float* __restrict__ rawA1,
    const float* __restrict__ rawAout,
    const float* __restrict__ W1,  const float* __restrict__ b1,
    const float* __restrict__ Wc0, const float* __restrict__ bc0,
    const float* __restrict__ Wc1, const float* __restrict__ bc1,
    const float* __restrict__ wout)
{
    __shared__ float sA0[1024], sA1[1024], sAout[32];
    const int t = threadIdx.x;
    for (int k = t; k < 1024; k += 256) { float v = sp_only(rawA0[k]); sA0[k] = v; g_tab[k] = v; }
    for (int k = t; k < 1024; k += 256) { float v = sp_only(rawA1[k]); sA1[k] = v; g_tab[1024 + k] = v; }
    if (t < 32) { float v = sp_only(rawAout[t]); sAout[t] = v; g_tab[4096 + t] = v; }
    __syncthreads();
    for (int k = t; k < 1024; k += 256) g_tab[2048 + k] = sA0[(k & 31) * 32 + (k >> 5)];
    for (int k = t; k < 1024; k += 256) g_tab[3072 + k] = sA1[(k & 31) * 32 + (k >> 5)];

    if (t < 32) {
        const int i = t;
        float sa, sc0v;
        float zi = sp_sig(b1[i], sa);
        float u = 0.0f;
        for (int j = 0; j < 32; j++) u = fmaf(sA0[i * 32 + j], __shfl(zi, j, 64), u);
        float su; float t0 = sp_sig(u, su);
        float d0 = kAct2 * t0 * su;
        float spc = sp_sig(bc0[i], sc0v);
        float zn = fmaf(kActScale * t0, t0, spc);
        float u1 = 0.0f;
        for (int j = 0; j < 32; j++) u1 = fmaf(sA1[i * 32 + j], __shfl(zn, j, 64), u1);
        float su1; float t1 = sp_sig(u1, su1);
        float d1 = sAout[i] * kAct2 * t1 * su1;
        float contrib = Wc1[2 * i] * sAout[i] * sig_only(bc1[i]);
        float g = 0.0f;
        for (int j = 0; j < 32; j++) g = fmaf(sA1[j * 32 + i], __shfl(d1, j, 64), g);
        contrib = fmaf(Wc0[2 * i], g * sc0v, contrib);
        float gu0 = g * d0;
        float ga = 0.0f;
        for (int j = 0; j < 32; j++) ga = fmaf(sA0[j * 32 + i], __shfl(gu0, j, 64), ga);
        ga *= sa;
        contrib = fmaf(W1[2 * i], ga, contrib);
        for (int off = 16; off >= 1; off >>= 1)
            contrib += __shfl_down(contrib, off, 32);
        if (i == 0) g_tab[4128] = wout[0] + contrib;
    }
}

// ---------------- main: one thread per row, fully scalarized -----------------
// R2/R3 post-mortem: VGPR_Count=60..64 despite a 128..170 budget => the
// private arrays were never promoted out of scratch (alloca not SROA'd),
// giving ~2.7x VALU instruction bloat. Fix: NO arrays, NO allocas -- 160
// named scalar locals + macro-expanded 32-term FMA chains. Table indices are
// compile-time constants => wave-uniform s_load, VALU stays pure FMA+trans.

#define RPT32(M) M(0) M(1) M(2) M(3) M(4) M(5) M(6) M(7) \
                 M(8) M(9) M(10) M(11) M(12) M(13) M(14) M(15) \
                 M(16) M(17) M(18) M(19) M(20) M(21) M(22) M(23) \
                 M(24) M(25) M(26) M(27) M(28) M(29) M(30) M(31)

// 32-term dot product of table row i with named scalars x_0..x_31
#define DOT32(A, i, x) \
 fmaf((A)[(i)*32+ 0], x##_0,  fmaf((A)[(i)*32+ 1], x##_1,  \
 fmaf((A)[(i)*32+ 2], x##_2,  fmaf((A)[(i)*32+ 3], x##_3,  \
 fmaf((A)[(i)*32+ 4], x##_4,  fmaf((A)[(i)*32+ 5], x##_5,  \
 fmaf((A)[(i)*32+ 6], x##_6,  fmaf((A)[(i)*32+ 7], x##_7,  \
 fmaf((A)[(i)*32+ 8], x##_8,  fmaf((A)[(i)*32+ 9], x##_9,  \
 fmaf((A)[(i)*32+10], x##_10, fmaf((A)[(i)*32+11], x##_11, \
 fmaf((A)[(i)*32+12], x##_12, fmaf((A)[(i)*32+13], x##_13, \
 fmaf((A)[(i)*32+14], x##_14, fmaf((A)[(i)*32+15], x##_15, \
 fmaf((A)[(i)*32+16], x##_16, fmaf((A)[(i)*32+17], x##_17, \
 fmaf((A)[(i)*32+18], x##_18, fmaf((A)[(i)*32+19], x##_19, \
 fmaf((A)[(i)*32+20], x##_20, fmaf((A)[(i)*32+21], x##_21, \
 fmaf((A)[(i)*32+22], x##_22, fmaf((A)[(i)*32+23], x##_23, \
 fmaf((A)[(i)*32+24], x##_24, fmaf((A)[(i)*32+25], x##_25, \
 fmaf((A)[(i)*32+26], x##_26, fmaf((A)[(i)*32+27], x##_27, \
 fmaf((A)[(i)*32+28], x##_28, fmaf((A)[(i)*32+29], x##_29, \
 fmaf((A)[(i)*32+30], x##_30, (A)[(i)*32+31] * x##_31 )))))))))))))))))))))))))))))))

__global__ __launch_bounds__(256, 3) void icnn_main(
    const float* __restrict__ eps,
    const float* __restrict__ W1,  const float* __restrict__ b1,
    const float* __restrict__ Wc0, const float* __restrict__ bc0,
    const float* __restrict__ Wc1, const float* __restrict__ bc1,
    const float* __restrict__ wout,
    float* __restrict__ out)
{
    const int row = blockIdx.x * 256 + threadIdx.x;

    const float e11 = eps[row * 3 + 0];
    const float e22 = eps[row * 3 + 1];
    const float e12 = eps[row * 3 + 2];
    const float x1 = e11 + e22;
    const float x2 = e11 * e11 + 2.0f * e12 * e12 + e22 * e22;

    const float* __restrict__ A0   = g_tab;
    const float* __restrict__ A1   = g_tab + 1024;
    const float* __restrict__ A0T  = g_tab + 2048;
    const float* __restrict__ A1T  = g_tab + 3072;
    const float* __restrict__ aout = g_tab + 4096;

    float g0 = wout[0], gq = wout[1];

#define DECL_Z(i)  float z_##i;
#define DECL_ZN(i) float zn_##i;
#define DECL_D0(i) float d0_##i;
#define DECL_D1(i) float d1_##i;
#define DECL_GG(i) float gg_##i;
    RPT32(DECL_Z) RPT32(DECL_ZN) RPT32(DECL_D0) RPT32(DECL_D1) RPT32(DECL_GG)

    // ---- L1 forward: z = softplus(W1 z0 + b1)
#define L1F(i) { float a = fmaf(W1[2*(i)], x1, fmaf(W1[2*(i)+1], x2, b1[(i)])); \
                 z_##i = sp_only(a); }
    RPT32(L1F)

    // ---- layer 0: u = A0 z; zn = ACT*sp(u)^2 + sp(c0); d0 = dz/du
#define L0S(i) { float u = DOT32(A0, i, z); \
                 float su; float t = sp_sig(u, su); \
                 d0_##i = kAct2 * t * su; \
                 float c = fmaf(Wc0[2*(i)], x1, fmaf(Wc0[2*(i)+1], x2, bc0[(i)])); \
                 zn_##i = fmaf(kActScale * t, t, sp_only(c)); }
    RPT32(L0S)

    // ---- layer 1: d1 = aout .* d sp^2/du1; fold c1-skip gradient now
#define L1S(i) { float u = DOT32(A1, i, zn); \
                 float su; float t = sp_sig(u, su); \
                 d1_##i = aout[(i)] * kAct2 * t * su; \
                 float c = fmaf(Wc1[2*(i)], x1, fmaf(Wc1[2*(i)+1], x2, bc1[(i)])); \
                 float w = aout[(i)] * sig_only(c); \
                 g0 = fmaf(Wc1[2*(i)], w, g0); \
                 gq = fmaf(Wc1[2*(i)+1], w, gq); }
    RPT32(L1S)

    // ---- backward through A1^T; fold layer-0 skip gradient; gate by d0.
    // NOTE: c recomputed with DIFFERENT association than L0S to block CSE
    // from keeping 32 extra values live.
#define B1S(i) { float acc = DOT32(A1T, i, d1); \
                 float c = fmaf(Wc0[2*(i)+1], x2, fmaf(Wc0[2*(i)], x1, bc0[(i)])); \
                 float w = acc * sig_only(c); \
                 g0 = fmaf(Wc0[2*(i)], w, g0); \
                 gq = fmaf(Wc0[2*(i)+1], w, gq); \
                 gg_##i = acc * d0_##i; }
    RPT32(B1S)

    // ---- backward through A0^T and the first layer (recompute sigmoid(a),
    // different association than L1F).
#define B0S(i) { float acc = DOT32(A0T, i, gg); \
                 float a = fmaf(W1[2*(i)+1], x2, fmaf(W1[2*(i)], x1, b1[(i)])); \
                 float ga = acc * sig_only(a); \
                 g0 = fmaf(W1[2*(i)], ga, g0); \
                 gq = fmaf(W1[2*(i)+1], ga, gq); }
    RPT32(B0S)

    const float cref = g_tab[4128];
    const float dI1 = g0 - cref;
    const float dI2 = gq;
    out[row * 3 + 0] = fmaf(2.0f * e11, dI2, dI1);
    out[row * 3 + 1] = fmaf(2.0f * e22, dI2, dI1);
    out[row * 3 + 2] = 2.0f * e12 * dI2;
}

extern "C" void kernel_launch(void* const* d_in, const int* in_sizes, int n_in,
                              void* d_out, int out_size, void* d_ws, size_t ws_size,
                              hipStream_t stream)
{
    (void)in_sizes; (void)n_in; (void)out_size; (void)d_ws; (void)ws_size;
    const float* eps    = (const float*)d_in[0];
    const float* W1     = (const float*)d_in[1];
    const float* b1     = (const float*)d_in[2];
    const float* rawA0  = (const float*)d_in[3];
    const float* rawA1  = (const float*)d_in[4];
    const float* Wc0    = (const float*)d_in[5];
    const float* bc0    = (const float*)d_in[6];
    const float* Wc1    = (const float*)d_in[7];
    const float* bc1    = (const float*)d_in[8];
    const float* rawAout= (const float*)d_in[9];
    const float* wout   = (const float*)d_in[10];
    float* out = (float*)d_out;

    icnn_prep<<<1, 256, 0, stream>>>(rawA0, rawA1, rawAout, W1, b1, Wc0, bc0, Wc1, bc1, wout);
    icnn_main<<<kBatch / 256, 256, 0, stream>>>(eps, W1, b1, Wc0, bc0, Wc1, bc1, wout, out);
}